// Round 1
// baseline (26258.270 us; speedup 1.0000x reference)
//
#include <hip/hip_runtime.h>
#include <math.h>

#define D 1024
#define DFF 4096
#define NH 16
#define DHH 64
#define BB 32
#define LQS 256
#define TT 40
#define CCOL 12
#define PPAR 64
#define FEDGE 6
#define S_MAIN 376
#define M_MAIN (BB * S_MAIN)  /* 12032 */
#define M_TC (BB * TT * CCOL) /* 15360 */

// ---------------- block reduction (256 threads = 4 waves) ----------------
__device__ __forceinline__ float block_sum_256(float v, float* sb) {
#pragma unroll
  for (int o = 32; o > 0; o >>= 1) v += __shfl_xor(v, o, 64);
  int w = threadIdx.x >> 6;
  if ((threadIdx.x & 63) == 0) sb[w] = v;
  __syncthreads();
  float r = sb[0] + sb[1] + sb[2] + sb[3];
  __syncthreads();
  return r;
}

// layer-norm a row of 1024 held as float4/thread. lnw: gamma at [0..1023], beta at [1024..2047]
__device__ __forceinline__ float4 ln_apply(float4 e, const float* __restrict__ lnw, int c, float* sb) {
  float s = e.x + e.y + e.z + e.w;
  s = block_sum_256(s, sb);
  float mean = s * (1.0f / 1024.0f);
  float dx = e.x - mean, dy = e.y - mean, dz = e.z - mean, dw = e.w - mean;
  float s2 = dx * dx + dy * dy + dz * dz + dw * dw;
  s2 = block_sum_256(s2, sb);
  float inv = 1.0f / sqrtf(s2 * (1.0f / 1024.0f) + 1e-12f);
  float4 g = *(const float4*)&lnw[c];
  float4 b = *(const float4*)&lnw[D + c];
  float4 o;
  o.x = dx * inv * g.x + b.x;
  o.y = dy * inv * g.y + b.y;
  o.z = dz * inv * g.z + b.z;
  o.w = dw * inv * g.w + b.w;
  return o;
}

// ---------------- embeddings ----------------
// one block per question token row; writes x[b*376 + s]
__global__ __launch_bounds__(256) void embed_q_kernel(
    const int* __restrict__ ids, const float* __restrict__ wemb, const float* __restrict__ pemb,
    const float* __restrict__ temb, const float* __restrict__ lnw, float* __restrict__ x) {
  __shared__ float sb[4];
  int row = blockIdx.x;           // 0..8191
  int b = row >> 8, s = row & 255;
  int id = ids[row];
  int c = threadIdx.x << 2;
  const float4 we = *(const float4*)&wemb[(size_t)id * D + c];
  const float4 pe = *(const float4*)&pemb[(size_t)s * D + c];
  const float4 te = *(const float4*)&temb[c];  // type 0
  float4 e;
  e.x = we.x + pe.x + te.x; e.y = we.y + pe.y + te.y;
  e.z = we.z + pe.z + te.z; e.w = we.w + pe.w + te.w;
  float4 o = ln_apply(e, lnw, c, sb);
  *(float4*)&x[((size_t)b * S_MAIN + s) * D + c] = o;
}

// one block per table-col token row (15360); writes tc[row]
__global__ __launch_bounds__(256) void embed_tc_kernel(
    const int* __restrict__ ids, const int* __restrict__ types, const float* __restrict__ wemb,
    const float* __restrict__ pemb, const float* __restrict__ temb, const float* __restrict__ lnw,
    float* __restrict__ tc) {
  __shared__ float sb[4];
  int row = blockIdx.x;  // 0..15359
  int id = ids[row];
  int tp = types[row];
  int cpos = row % CCOL;
  int c = threadIdx.x << 2;
  const float4 we = *(const float4*)&wemb[(size_t)id * D + c];
  const float4 pe = *(const float4*)&pemb[(size_t)cpos * D + c];
  const float4 te = *(const float4*)&temb[(size_t)tp * D + c];
  float4 e;
  e.x = we.x + pe.x + te.x; e.y = we.y + pe.y + te.y;
  e.z = we.z + pe.z + te.z; e.w = we.w + pe.w + te.w;
  float4 o = ln_apply(e, lnw, c, sb);
  *(float4*)&tc[(size_t)row * D + c] = o;
}

// assemble: block per (b, jj) jj in [0,120); reads tc (post-FK), writes x[b*376+256+jj]
__global__ __launch_bounds__(256) void assemble_kernel(
    const float* __restrict__ tc, const float* __restrict__ pemb, const float* __restrict__ temb,
    const float* __restrict__ lnw, float* __restrict__ x) {
  __shared__ float sb[4];
  int idx = blockIdx.x;  // 0..B*120-1
  int b = idx / 120, jj = idx % 120;
  int t = jj / 3, i = jj % 3;
  int c = threadIdx.x << 2;
  size_t src = (((size_t)(b * TT + t)) * CCOL + i) * D + c;
  const float4 sv = *(const float4*)&tc[src];
  const float4 pe = *(const float4*)&pemb[(size_t)(LQS + jj) * D + c];
  const float4 te = *(const float4*)&temb[D + c];  // type 1
  float4 e;
  e.x = sv.x + pe.x + te.x; e.y = sv.y + pe.y + te.y;
  e.z = sv.z + pe.z + te.z; e.w = sv.w + pe.w + te.w;
  float4 o = ln_apply(e, lnw, c, sb);
  *(float4*)&x[((size_t)b * S_MAIN + LQS + jj) * D + c] = o;
}

// ---------------- layer norm (in-place, one block per row) ----------------
__global__ __launch_bounds__(256) void ln_kernel(float* __restrict__ x, const float* __restrict__ lnw) {
  __shared__ float sb[4];
  int c = threadIdx.x << 2;
  size_t base = (size_t)blockIdx.x * D + c;
  float4 v = *(float4*)&x[base];
  float4 o = ln_apply(v, lnw, c, sb);
  *(float4*)&x[base] = o;
}

// ---------------- fp32 GEMM: C = [resid +] act(A@W + bias) ----------------
// A[M,K] row-major, W[K,N] row-major. M,N,K % 64 == 0 (K%16==0).
template <int ACT, int RESID>
__global__ __launch_bounds__(256) void gemm_kernel(
    const float* __restrict__ A, const float* __restrict__ W, const float* __restrict__ bias,
    const float* __restrict__ Rs, float* __restrict__ C, int M, int N, int K) {
  __shared__ float As[16][68];  // transposed A tile: As[k][m], 68-pad keeps float4 alignment
  __shared__ float Ws[16][64];
  const int tid = threadIdx.x;
  const int tx = tid & 15, ty = tid >> 4;
  const int bm = blockIdx.y << 6, bn = blockIdx.x << 6;
  const int ar = tid >> 2, ac4 = (tid & 3) << 2;
  const int wr = tid >> 4, wc4 = (tid & 15) << 2;
  const float* Ap = A + (size_t)(bm + ar) * K + ac4;
  const float* Wp = W + (size_t)wr * N + bn + wc4;
  float acc[4][4] = {};
  for (int k0 = 0; k0 < K; k0 += 16) {
    float4 av = *(const float4*)(Ap + k0);
    float4 wv = *(const float4*)(Wp + (size_t)k0 * N);
    __syncthreads();
    As[ac4 + 0][ar] = av.x;
    As[ac4 + 1][ar] = av.y;
    As[ac4 + 2][ar] = av.z;
    As[ac4 + 3][ar] = av.w;
    *(float4*)&Ws[wr][wc4] = wv;
    __syncthreads();
#pragma unroll
    for (int kk = 0; kk < 16; ++kk) {
      float4 a4 = *(const float4*)&As[kk][ty << 2];
      float4 w4 = *(const float4*)&Ws[kk][tx << 2];
      acc[0][0] += a4.x * w4.x; acc[0][1] += a4.x * w4.y; acc[0][2] += a4.x * w4.z; acc[0][3] += a4.x * w4.w;
      acc[1][0] += a4.y * w4.x; acc[1][1] += a4.y * w4.y; acc[1][2] += a4.y * w4.z; acc[1][3] += a4.y * w4.w;
      acc[2][0] += a4.z * w4.x; acc[2][1] += a4.z * w4.y; acc[2][2] += a4.z * w4.z; acc[2][3] += a4.z * w4.w;
      acc[3][0] += a4.w * w4.x; acc[3][1] += a4.w * w4.y; acc[3][2] += a4.w * w4.z; acc[3][3] += a4.w * w4.w;
    }
  }
  const float4 bv = *(const float4*)&bias[bn + (tx << 2)];
#pragma unroll
  for (int i = 0; i < 4; ++i) {
    int row = bm + (ty << 2) + i;
    size_t off = (size_t)row * N + bn + (tx << 2);
    float4 rv;
    rv.x = acc[i][0] + bv.x;
    rv.y = acc[i][1] + bv.y;
    rv.z = acc[i][2] + bv.z;
    rv.w = acc[i][3] + bv.w;
    if (ACT == 1) {  // exact gelu
      rv.x = 0.5f * rv.x * (1.0f + erff(rv.x * 0.7071067811865475f));
      rv.y = 0.5f * rv.y * (1.0f + erff(rv.y * 0.7071067811865475f));
      rv.z = 0.5f * rv.z * (1.0f + erff(rv.z * 0.7071067811865475f));
      rv.w = 0.5f * rv.w * (1.0f + erff(rv.w * 0.7071067811865475f));
    }
    if (RESID) {
      float4 xr = *(const float4*)(Rs + off);
      rv.x += xr.x; rv.y += xr.y; rv.z += xr.z; rv.w += xr.w;
    }
    *(float4*)(C + off) = rv;
  }
}

// ---------------- flash attention (fp32), QT=KT=32, DH=64, H=16 ----------------
// q/k/v/y: [Bseq*S, 1024], head h at cols h*64..h*64+63. grid (ceil(S/32), 16, Bseq)
__global__ __launch_bounds__(256) void attn_kernel(
    const float* __restrict__ qg, const float* __restrict__ kg, const float* __restrict__ vg,
    float* __restrict__ yg, int S) {
  const int qt = blockIdx.x, h = blockIdx.y, bs = blockIdx.z;
  const int tid = threadIdx.x;
  const int r = tid >> 3;  // q row in tile (0..31)
  const int j = tid & 7;   // 8 threads per row
  __shared__ float qs[32][68], ks[32][68], vs[32][68];
  __shared__ float ps[32][36];
#pragma unroll
  for (int t = tid; t < 512; t += 256) {
    int rr = t >> 4, c4 = (t & 15) << 2;
    int row = qt * 32 + rr;
    float4 val = make_float4(0.f, 0.f, 0.f, 0.f);
    if (row < S) val = *(const float4*)&qg[((size_t)bs * S + row) * D + h * DHH + c4];
    *(float4*)&qs[rr][c4] = val;
  }
  float o0 = 0, o1 = 0, o2 = 0, o3 = 0, o4 = 0, o5 = 0, o6 = 0, o7 = 0;
  float m = -1e30f, l = 0.f;
  const int nkt = (S + 31) >> 5;
  for (int kt = 0; kt < nkt; ++kt) {
    __syncthreads();
#pragma unroll
    for (int t = tid; t < 512; t += 256) {
      int rr = t >> 4, c4 = (t & 15) << 2;
      int row = kt * 32 + rr;
      float4 kv = make_float4(0.f, 0.f, 0.f, 0.f), vv = kv;
      if (row < S) {
        size_t base = ((size_t)bs * S + row) * D + h * DHH + c4;
        kv = *(const float4*)&kg[base];
        vv = *(const float4*)&vg[base];
      }
      *(float4*)&ks[rr][c4] = kv;
      *(float4*)&vs[rr][c4] = vv;
    }
    __syncthreads();
    const int kk0 = j << 2;
    float s0 = 0, s1 = 0, s2 = 0, s3 = 0;
#pragma unroll
    for (int d = 0; d < 64; d += 4) {
      float4 qv = *(const float4*)&qs[r][d];
      float4 ka = *(const float4*)&ks[kk0 + 0][d];
      float4 kb = *(const float4*)&ks[kk0 + 1][d];
      float4 kc = *(const float4*)&ks[kk0 + 2][d];
      float4 kd = *(const float4*)&ks[kk0 + 3][d];
      s0 += qv.x * ka.x + qv.y * ka.y + qv.z * ka.z + qv.w * ka.w;
      s1 += qv.x * kb.x + qv.y * kb.y + qv.z * kb.z + qv.w * kb.w;
      s2 += qv.x * kc.x + qv.y * kc.y + qv.z * kc.z + qv.w * kc.w;
      s3 += qv.x * kd.x + qv.y * kd.y + qv.z * kd.z + qv.w * kd.w;
    }
    const int kvalid = S - kt * 32;
    s0 = (kk0 + 0 < kvalid) ? s0 * 0.125f : -1e30f;
    s1 = (kk0 + 1 < kvalid) ? s1 * 0.125f : -1e30f;
    s2 = (kk0 + 2 < kvalid) ? s2 * 0.125f : -1e30f;
    s3 = (kk0 + 3 < kvalid) ? s3 * 0.125f : -1e30f;
    float mx = fmaxf(fmaxf(s0, s1), fmaxf(s2, s3));
    mx = fmaxf(mx, __shfl_xor(mx, 1, 64));
    mx = fmaxf(mx, __shfl_xor(mx, 2, 64));
    mx = fmaxf(mx, __shfl_xor(mx, 4, 64));
    float mnew = fmaxf(m, mx);
    float sc = __expf(m - mnew);
    float p0 = __expf(s0 - mnew), p1 = __expf(s1 - mnew);
    float p2 = __expf(s2 - mnew), p3 = __expf(s3 - mnew);
    float rs = p0 + p1 + p2 + p3;
    rs += __shfl_xor(rs, 1, 64);
    rs += __shfl_xor(rs, 2, 64);
    rs += __shfl_xor(rs, 4, 64);
    l = l * sc + rs;
    m = mnew;
    o0 *= sc; o1 *= sc; o2 *= sc; o3 *= sc; o4 *= sc; o5 *= sc; o6 *= sc; o7 *= sc;
    ps[r][kk0 + 0] = p0; ps[r][kk0 + 1] = p1; ps[r][kk0 + 2] = p2; ps[r][kk0 + 3] = p3;
    __syncthreads();
    const int c0 = j << 3;
#pragma unroll
    for (int kk = 0; kk < 32; ++kk) {
      float p = ps[r][kk];
      float4 va = *(const float4*)&vs[kk][c0];
      float4 vb = *(const float4*)&vs[kk][c0 + 4];
      o0 += p * va.x; o1 += p * va.y; o2 += p * va.z; o3 += p * va.w;
      o4 += p * vb.x; o5 += p * vb.y; o6 += p * vb.z; o7 += p * vb.w;
    }
  }
  int qrow = qt * 32 + r;
  if (qrow < S) {
    float inv = 1.0f / l;
    float4 ra, rb;
    ra.x = o0 * inv; ra.y = o1 * inv; ra.z = o2 * inv; ra.w = o3 * inv;
    rb.x = o4 * inv; rb.y = o5 * inv; rb.z = o6 * inv; rb.w = o7 * inv;
    size_t base = ((size_t)bs * S + qrow) * D + h * DHH + (j << 3);
    *(float4*)&yg[base] = ra;
    *(float4*)&yg[base + 4] = rb;
  }
}

// ---------------- foreign-key scan pieces ----------------
__global__ __launch_bounds__(256) void zero_kernel(float* __restrict__ p, int n) {
  int i = blockIdx.x * 256 + threadIdx.x;
  if (i < n) p[i] = 0.f;
}

// grid (4 colchunks, 32 batches, 4 kchunks). scr[b][i][col] += partial dot
__global__ __launch_bounds__(256) void fk_compute(
    const float* __restrict__ tc, const int* __restrict__ pnums, const int* __restrict__ fkeys,
    const float* __restrict__ W, float* __restrict__ scr, int e, int which) {
  const int tid = threadIdx.x;
  const int b = blockIdx.y;
  const int i0 = fkeys[(b * FEDGE + e) * 2 + 0];
  const int i1 = fkeys[(b * FEDGE + e) * 2 + 1];
  const int fp = pnums[b * PPAR + i0];
  const int pp = pnums[b * PPAR + i1];
  const int src = which ? fp : pp;
  const int k0 = blockIdx.z << 8;
  __shared__ float sa[3][256];
#pragma unroll
  for (int i = 0; i < 3; ++i)
    sa[i][tid] = tc[(((size_t)(b * TT + src)) * CCOL + i) * D + k0 + tid];
  __syncthreads();
  const int col = (blockIdx.x << 8) + tid;
  float a0 = 0, a1 = 0, a2 = 0;
#pragma unroll 8
  for (int kk = 0; kk < 256; ++kk) {
    float w = W[(size_t)(k0 + kk) * D + col];
    a0 += sa[0][kk] * w;
    a1 += sa[1][kk] * w;
    a2 += sa[2][kk] * w;
  }
  atomicAdd(&scr[(b * 3 + 0) * D + col], a0);
  atomicAdd(&scr[(b * 3 + 1) * D + col], a1);
  atomicAdd(&scr[(b * 3 + 2) * D + col], a2);
}

// grid 384: tc[b,dst,i,:] += tanh(scr + bias)
__global__ __launch_bounds__(256) void fk_add(
    float* __restrict__ tc, const int* __restrict__ pnums, const int* __restrict__ fkeys,
    const float* __restrict__ bias, const float* __restrict__ scr, int e, int which) {
  int idx = blockIdx.x * 256 + threadIdx.x;  // 0..98303
  int col = idx & 1023;
  int bi = idx >> 10;
  int b = bi / 3, i = bi % 3;
  const int i0 = fkeys[(b * FEDGE + e) * 2 + 0];
  const int i1 = fkeys[(b * FEDGE + e) * 2 + 1];
  const int fp = pnums[b * PPAR + i0];
  const int pp = pnums[b * PPAR + i1];
  const int dst = which ? pp : fp;
  float val = tanhf(scr[idx] + bias[col]);
  tc[(((size_t)(b * TT + dst)) * CCOL + i) * D + col] += val;
}

// ---------------- host-side orchestration ----------------
static void gemm(const float* A, const float* W, const float* bias, const float* Rs, float* C,
                 int M, int N, int K, int act, int resid, hipStream_t st) {
  dim3 g(N >> 6, M >> 6);
  if (act == 1)
    gemm_kernel<1, 0><<<g, 256, 0, st>>>(A, W, bias, Rs, C, M, N, K);
  else if (resid)
    gemm_kernel<0, 1><<<g, 256, 0, st>>>(A, W, bias, Rs, C, M, N, K);
  else
    gemm_kernel<0, 0><<<g, 256, 0, st>>>(A, W, bias, Rs, C, M, N, K);
}

static void run_layer(float* xp, int l, int M, int Bseq, int S,
                      const float* qkvw, const float* qkvb, const float* ow, const float* ob,
                      const float* ln1, const float* w1, const float* b1,
                      const float* w2, const float* b2, const float* ln2,
                      float* q, float* k, float* v, float* y, float* h, hipStream_t st) {
  const size_t dd = (size_t)D * D;
  gemm(xp, qkvw + (size_t)(l * 3 + 0) * dd, qkvb + (size_t)(l * 3 + 0) * D, nullptr, q, M, D, D, 0, 0, st);
  gemm(xp, qkvw + (size_t)(l * 3 + 1) * dd, qkvb + (size_t)(l * 3 + 1) * D, nullptr, k, M, D, D, 0, 0, st);
  gemm(xp, qkvw + (size_t)(l * 3 + 2) * dd, qkvb + (size_t)(l * 3 + 2) * D, nullptr, v, M, D, D, 0, 0, st);
  attn_kernel<<<dim3((S + 31) / 32, NH, Bseq), 256, 0, st>>>(q, k, v, y, S);
  gemm(y, ow + (size_t)l * dd, ob + (size_t)l * D, xp, xp, M, D, D, 0, 1, st);
  ln_kernel<<<M, 256, 0, st>>>(xp, ln1 + (size_t)l * 2 * D);
  gemm(xp, w1 + (size_t)l * D * DFF, b1 + (size_t)l * DFF, nullptr, h, M, DFF, D, 1, 0, st);
  gemm(h, w2 + (size_t)l * DFF * D, b2 + (size_t)l * D, xp, xp, M, D, DFF, 0, 1, st);
  ln_kernel<<<M, 256, 0, st>>>(xp, ln2 + (size_t)l * 2 * D);
}

extern "C" void kernel_launch(void* const* d_in, const int* in_sizes, int n_in,
                              void* d_out, int out_size, void* d_ws, size_t ws_size,
                              hipStream_t stream) {
  (void)in_sizes; (void)n_in; (void)out_size; (void)ws_size;
  const int* input_ids = (const int*)d_in[0];
  const int* table_cols = (const int*)d_in[1];
  const int* tc_types = (const int*)d_in[2];
  const int* pnums = (const int*)d_in[3];
  const int* fkeys = (const int*)d_in[4];
  const float* wemb = (const float*)d_in[9];
  const float* pemb = (const float*)d_in[10];
  const float* temb = (const float*)d_in[11];
  const float* embln = (const float*)d_in[12];
  const float* qkvw = (const float*)d_in[13];
  const float* qkvb = (const float*)d_in[14];
  const float* ow = (const float*)d_in[15];
  const float* ob = (const float*)d_in[16];
  const float* ln1 = (const float*)d_in[17];
  const float* w1 = (const float*)d_in[18];
  const float* b1 = (const float*)d_in[19];
  const float* w2 = (const float*)d_in[20];
  const float* b2 = (const float*)d_in[21];
  const float* ln2 = (const float*)d_in[22];
  const float* primw = (const float*)d_in[23];
  const float* primb = (const float*)d_in[24];
  const float* forw = (const float*)d_in[25];
  const float* forb = (const float*)d_in[26];

  float* x = (float*)d_out;  // [32, 376, 1024] — computed in place
  const size_t SZ = (size_t)M_TC * D;  // 15.7M floats
  float* q = (float*)d_ws;
  float* kb = q + SZ;
  float* vb = kb + SZ;
  float* yb = vb + SZ;
  float* h = q;            // FFN hidden overlays q..y (needs 4*SZ = M_TC*DFF)
  float* tc = yb + SZ;     // table-col token states [15360, 1024]
  float* fks = tc + SZ;    // FK scratch [32*3*1024]

  // embeddings
  embed_q_kernel<<<BB * LQS, 256, 0, stream>>>(input_ids, wemb, pemb, temb, embln, x);
  embed_tc_kernel<<<M_TC, 256, 0, stream>>>(table_cols, tc_types, wemb, pemb, temb, embln, tc);

  // layer 0 on table-col sequences (1280 seqs of length 12)
  run_layer(tc, 0, M_TC, BB * TT, CCOL, qkvw, qkvb, ow, ob, ln1, w1, b1, w2, b2, ln2,
            q, kb, vb, yb, h, stream);

  // foreign-key sequential scan: 6 edges x 2 sub-steps
  for (int e = 0; e < FEDGE; ++e) {
    for (int which = 0; which < 2; ++which) {
      zero_kernel<<<384, 256, 0, stream>>>(fks, BB * 3 * D);
      fk_compute<<<dim3(4, BB, 4), 256, 0, stream>>>(tc, pnums, fkeys,
                                                     which ? forw : primw, fks, e, which);
      fk_add<<<384, 256, 0, stream>>>(tc, pnums, fkeys, which ? forb : primb, fks, e, which);
    }
  }

  // ragged assembly into x rows 256..375 per batch
  assemble_kernel<<<BB * 120, 256, 0, stream>>>(tc, pemb, temb, embln, x);

  // main encoder layers 1..4 on [32, 376, 1024]
  for (int l = 1; l < 5; ++l)
    run_layer(x, l, M_MAIN, BB, S_MAIN, qkvw, qkvb, ow, ob, ln1, w1, b1, w2, b2, ln2,
              q, kb, vb, yb, h, stream);
}

// Round 3
// 9169.991 us; speedup vs baseline: 2.8635x; 2.8635x over previous
//
#include <hip/hip_runtime.h>
#include <math.h>

#define D 1024
#define DFF 4096
#define NH 16
#define DHH 64
#define BB 32
#define LQS 256
#define TT 40
#define CCOL 12
#define PPAR 64
#define FEDGE 6
#define S_MAIN 376
#define M_MAIN (BB * S_MAIN)  /* 12032 */
#define M_TC (BB * TT * CCOL) /* 15360 */

using short8v = __attribute__((ext_vector_type(8))) short;
using bf16x8 = __attribute__((ext_vector_type(8))) __bf16;
using f32x4 = __attribute__((ext_vector_type(4))) float;

// ---------------- bf16 split helpers ----------------
__device__ __forceinline__ unsigned short bf16rne(float x) {
  unsigned u = __builtin_bit_cast(unsigned, x);
  unsigned r = (u + 0x7fffu + ((u >> 16) & 1u)) >> 16;
  return (unsigned short)r;
}
__device__ __forceinline__ float bf16tof(unsigned short h) {
  unsigned u = ((unsigned)h) << 16;
  return __builtin_bit_cast(float, u);
}

__device__ __forceinline__ void gload16(const void* g, void* l) {
  __builtin_amdgcn_global_load_lds((const __attribute__((address_space(1))) void*)g,
                                   (__attribute__((address_space(3))) void*)l, 16, 0, 0);
}

// ---------------- block reduction (256 threads = 4 waves) ----------------
__device__ __forceinline__ float block_sum_256(float v, float* sb) {
#pragma unroll
  for (int o = 32; o > 0; o >>= 1) v += __shfl_xor(v, o, 64);
  int w = threadIdx.x >> 6;
  if ((threadIdx.x & 63) == 0) sb[w] = v;
  __syncthreads();
  float r = sb[0] + sb[1] + sb[2] + sb[3];
  __syncthreads();
  return r;
}

__device__ __forceinline__ float4 ln_apply(float4 e, const float* __restrict__ lnw, int c, float* sb) {
  float s = e.x + e.y + e.z + e.w;
  s = block_sum_256(s, sb);
  float mean = s * (1.0f / 1024.0f);
  float dx = e.x - mean, dy = e.y - mean, dz = e.z - mean, dw = e.w - mean;
  float s2 = dx * dx + dy * dy + dz * dz + dw * dw;
  s2 = block_sum_256(s2, sb);
  float inv = 1.0f / sqrtf(s2 * (1.0f / 1024.0f) + 1e-12f);
  float4 g = *(const float4*)&lnw[c];
  float4 b = *(const float4*)&lnw[D + c];
  float4 o;
  o.x = dx * inv * g.x + b.x;
  o.y = dy * inv * g.y + b.y;
  o.z = dz * inv * g.z + b.z;
  o.w = dw * inv * g.w + b.w;
  return o;
}

// ---------------- embeddings ----------------
__global__ __launch_bounds__(256) void embed_q_kernel(
    const int* __restrict__ ids, const float* __restrict__ wemb, const float* __restrict__ pemb,
    const float* __restrict__ temb, const float* __restrict__ lnw, float* __restrict__ x) {
  __shared__ float sb[4];
  int row = blockIdx.x;
  int b = row >> 8, s = row & 255;
  int id = ids[row];
  int c = threadIdx.x << 2;
  const float4 we = *(const float4*)&wemb[(size_t)id * D + c];
  const float4 pe = *(const float4*)&pemb[(size_t)s * D + c];
  const float4 te = *(const float4*)&temb[c];
  float4 e;
  e.x = we.x + pe.x + te.x; e.y = we.y + pe.y + te.y;
  e.z = we.z + pe.z + te.z; e.w = we.w + pe.w + te.w;
  float4 o = ln_apply(e, lnw, c, sb);
  *(float4*)&x[((size_t)b * S_MAIN + s) * D + c] = o;
}

__global__ __launch_bounds__(256) void embed_tc_kernel(
    const int* __restrict__ ids, const int* __restrict__ types, const float* __restrict__ wemb,
    const float* __restrict__ pemb, const float* __restrict__ temb, const float* __restrict__ lnw,
    float* __restrict__ tc) {
  __shared__ float sb[4];
  int row = blockIdx.x;
  int id = ids[row];
  int tp = types[row];
  int cpos = row % CCOL;
  int c = threadIdx.x << 2;
  const float4 we = *(const float4*)&wemb[(size_t)id * D + c];
  const float4 pe = *(const float4*)&pemb[(size_t)cpos * D + c];
  const float4 te = *(const float4*)&temb[(size_t)tp * D + c];
  float4 e;
  e.x = we.x + pe.x + te.x; e.y = we.y + pe.y + te.y;
  e.z = we.z + pe.z + te.z; e.w = we.w + pe.w + te.w;
  float4 o = ln_apply(e, lnw, c, sb);
  *(float4*)&tc[(size_t)row * D + c] = o;
}

__global__ __launch_bounds__(256) void assemble_kernel(
    const float* __restrict__ tc, const float* __restrict__ pemb, const float* __restrict__ temb,
    const float* __restrict__ lnw, float* __restrict__ x) {
  __shared__ float sb[4];
  int idx = blockIdx.x;
  int b = idx / 120, jj = idx % 120;
  int t = jj / 3, i = jj % 3;
  int c = threadIdx.x << 2;
  size_t src = (((size_t)(b * TT + t)) * CCOL + i) * D + c;
  const float4 sv = *(const float4*)&tc[src];
  const float4 pe = *(const float4*)&pemb[(size_t)(LQS + jj) * D + c];
  const float4 te = *(const float4*)&temb[D + c];
  float4 e;
  e.x = sv.x + pe.x + te.x; e.y = sv.y + pe.y + te.y;
  e.z = sv.z + pe.z + te.z; e.w = sv.w + pe.w + te.w;
  float4 o = ln_apply(e, lnw, c, sb);
  *(float4*)&x[((size_t)b * S_MAIN + LQS + jj) * D + c] = o;
}

__global__ __launch_bounds__(256) void ln_kernel(float* __restrict__ x, const float* __restrict__ lnw) {
  __shared__ float sb[4];
  int c = threadIdx.x << 2;
  size_t base = (size_t)blockIdx.x * D + c;
  float4 v = *(float4*)&x[base];
  float4 o = ln_apply(v, lnw, c, sb);
  *(float4*)&x[base] = o;
}

// ---------------- fp32 -> bf16 hi/lo split (same layout) ----------------
__global__ __launch_bounds__(256) void split_kernel(const float* __restrict__ in,
    unsigned short* __restrict__ hi, unsigned short* __restrict__ lo, int n4) {
  int i = blockIdx.x * 256 + threadIdx.x;
  int stride = gridDim.x * 256;
  for (; i < n4; i += stride) {
    float4 v = ((const float4*)in)[i];
    ushort4 h, L;
    h.x = bf16rne(v.x); L.x = bf16rne(v.x - bf16tof(h.x));
    h.y = bf16rne(v.y); L.y = bf16rne(v.y - bf16tof(h.y));
    h.z = bf16rne(v.z); L.z = bf16rne(v.z - bf16tof(h.z));
    h.w = bf16rne(v.w); L.w = bf16rne(v.w - bf16tof(h.w));
    ((ushort4*)hi)[i] = h;
    ((ushort4*)lo)[i] = L;
  }
}

// W [K][N] fp32 -> Wt hi/lo [N][K] bf16 (transpose + split)
__global__ __launch_bounds__(256) void splitT_kernel(const float* __restrict__ W,
    unsigned short* __restrict__ hi, unsigned short* __restrict__ lo, int K, int N) {
  __shared__ float tile[32][33];
  int k0 = blockIdx.y << 5, n0 = blockIdx.x << 5;
  int rr = threadIdx.x >> 5, cc = threadIdx.x & 31;
#pragma unroll
  for (int i = 0; i < 4; ++i)
    tile[rr + i * 8][cc] = W[(size_t)(k0 + rr + i * 8) * N + n0 + cc];
  __syncthreads();
#pragma unroll
  for (int i = 0; i < 4; ++i) {
    float v = tile[cc][rr + i * 8];
    unsigned short h = bf16rne(v);
    size_t off = (size_t)(n0 + rr + i * 8) * K + k0 + cc;
    hi[off] = h;
    lo[off] = bf16rne(v - bf16tof(h));
  }
}

// ---------------- MFMA GEMM: C = [resid +] act(Ah,Al @ (Bh,Bl)^T + bias) ----------------
// A hi/lo: [M][K] bf16. B hi/lo: [N][K] bf16 (pre-transposed weight). 3-term split product.
// MODE 0: bias -> f32 C. MODE 1: bias + resid -> f32 C. MODE 2: bias + gelu -> bf16 hi/lo Ch/Cl.
template <int MODE>
__global__ __launch_bounds__(256) void mfma_gemm(
    const unsigned short* __restrict__ Ah, const unsigned short* __restrict__ Al,
    const unsigned short* __restrict__ Bh, const unsigned short* __restrict__ Bl,
    const float* __restrict__ bias, const float* __restrict__ Rs,
    float* __restrict__ Co, unsigned short* __restrict__ Ch, unsigned short* __restrict__ Cl,
    int M, int N, int K) {
  __shared__ __align__(16) unsigned short ls[4][128 * 32];  // Ah, Al, Bh, Bl tiles; [row][k]
  const int t = threadIdx.x;
  const int l = t & 63;
  const int w = t >> 6;
  const int wr = (w >> 1) << 6;  // wave row offset (0/64)
  const int wc = (w & 1) << 6;   // wave col offset (0/64)
  const int bm = blockIdx.y << 7, bn = blockIdx.x << 7;

  // staging: chunk = issue*256 + t; row = chunk>>2, kchunk = chunk&3 (8 bf16 = 16B per chunk)
  const int r0 = t >> 2, c0 = (t & 3) << 3;
  const int r1 = r0 + 64;  // (t+256)>>2
  const int lb0 = (t & 192) << 3;          // lds ushort offset of wave's chunk base, issue 0
  const int lb1 = (256 + (t & 192)) << 3;  // issue 1
  const size_t ga0 = (size_t)(bm + r0) * K + c0;
  const size_t ga1 = (size_t)(bm + r1) * K + c0;
  const size_t gb0 = (size_t)(bn + r0) * K + c0;
  const size_t gb1 = (size_t)(bn + r1) * K + c0;

  f32x4 acc[4][4];
#pragma unroll
  for (int m = 0; m < 4; ++m)
#pragma unroll
    for (int n = 0; n < 4; ++n) acc[m][n] = f32x4{0.f, 0.f, 0.f, 0.f};

  const int frk = (l >> 4) << 3;  // k offset of this lane's fragment (0,8,16,24)
  const int fr = l & 15;          // row/col within 16-tile

  for (int k0 = 0; k0 < K; k0 += 32) {
    __syncthreads();
    gload16(Ah + ga0 + k0, &ls[0][lb0]);
    gload16(Ah + ga1 + k0, &ls[0][lb1]);
    gload16(Al + ga0 + k0, &ls[1][lb0]);
    gload16(Al + ga1 + k0, &ls[1][lb1]);
    gload16(Bh + gb0 + k0, &ls[2][lb0]);
    gload16(Bh + gb1 + k0, &ls[2][lb1]);
    gload16(Bl + gb0 + k0, &ls[3][lb0]);
    gload16(Bl + gb1 + k0, &ls[3][lb1]);
    __syncthreads();  // drains vmcnt(0) before barrier -> LDS tiles complete

    short8v ah[4], al[4], bh[4], bl[4];
#pragma unroll
    for (int m = 0; m < 4; ++m) {
      int ro = ((wr + m * 16 + fr) << 5) + frk;
      ah[m] = *(const short8v*)&ls[0][ro];
      al[m] = *(const short8v*)&ls[1][ro];
    }
#pragma unroll
    for (int n = 0; n < 4; ++n) {
      int ro = ((wc + n * 16 + fr) << 5) + frk;
      bh[n] = *(const short8v*)&ls[2][ro];
      bl[n] = *(const short8v*)&ls[3][ro];
    }
#pragma unroll
    for (int m = 0; m < 4; ++m)
#pragma unroll
      for (int n = 0; n < 4; ++n) {
        acc[m][n] = __builtin_amdgcn_mfma_f32_16x16x32_bf16(
            __builtin_bit_cast(bf16x8, ah[m]), __builtin_bit_cast(bf16x8, bh[n]), acc[m][n], 0, 0, 0);
        acc[m][n] = __builtin_amdgcn_mfma_f32_16x16x32_bf16(
            __builtin_bit_cast(bf16x8, al[m]), __builtin_bit_cast(bf16x8, bh[n]), acc[m][n], 0, 0, 0);
        acc[m][n] = __builtin_amdgcn_mfma_f32_16x16x32_bf16(
            __builtin_bit_cast(bf16x8, ah[m]), __builtin_bit_cast(bf16x8, bl[n]), acc[m][n], 0, 0, 0);
      }
  }

  // epilogue: C/D layout col = lane&15, row = (lane>>4)*4 + reg  [m89-verified]
  const int cr = (l >> 4) << 2;
#pragma unroll
  for (int n = 0; n < 4; ++n) {
    int col = bn + wc + n * 16 + fr;
    float bv = bias[col];
#pragma unroll
    for (int m = 0; m < 4; ++m) {
#pragma unroll
      for (int j = 0; j < 4; ++j) {
        int row = bm + wr + m * 16 + cr + j;
        size_t off = (size_t)row * N + col;
        float v = acc[m][n][j] + bv;
        if (MODE == 1) v += Rs[off];
        if (MODE == 2) {
          v = 0.5f * v * (1.0f + erff(v * 0.7071067811865475f));
          unsigned short h = bf16rne(v);
          Ch[off] = h;
          Cl[off] = bf16rne(v - bf16tof(h));
        } else {
          Co[off] = v;
        }
      }
    }
  }
}

// ---------------- flash attention (fp32) ----------------
__global__ __launch_bounds__(256) void attn_kernel(
    const float* __restrict__ qg, const float* __restrict__ kg, const float* __restrict__ vg,
    float* __restrict__ yg, int S) {
  const int qt = blockIdx.x, h = blockIdx.y, bs = blockIdx.z;
  const int tid = threadIdx.x;
  const int r = tid >> 3;
  const int j = tid & 7;
  __shared__ float qs[32][68], ks[32][68], vs[32][68];
  __shared__ float ps[32][36];
#pragma unroll
  for (int t = tid; t < 512; t += 256) {
    int rr = t >> 4, c4 = (t & 15) << 2;
    int row = qt * 32 + rr;
    float4 val = make_float4(0.f, 0.f, 0.f, 0.f);
    if (row < S) val = *(const float4*)&qg[((size_t)bs * S + row) * D + h * DHH + c4];
    *(float4*)&qs[rr][c4] = val;
  }
  float o0 = 0, o1 = 0, o2 = 0, o3 = 0, o4 = 0, o5 = 0, o6 = 0, o7 = 0;
  float m = -1e30f, l = 0.f;
  const int nkt = (S + 31) >> 5;
  for (int kt = 0; kt < nkt; ++kt) {
    __syncthreads();
#pragma unroll
    for (int t = tid; t < 512; t += 256) {
      int rr = t >> 4, c4 = (t & 15) << 2;
      int row = kt * 32 + rr;
      float4 kv = make_float4(0.f, 0.f, 0.f, 0.f), vv = kv;
      if (row < S) {
        size_t base = ((size_t)bs * S + row) * D + h * DHH + c4;
        kv = *(const float4*)&kg[base];
        vv = *(const float4*)&vg[base];
      }
      *(float4*)&ks[rr][c4] = kv;
      *(float4*)&vs[rr][c4] = vv;
    }
    __syncthreads();
    const int kk0 = j << 2;
    float s0 = 0, s1 = 0, s2 = 0, s3 = 0;
#pragma unroll
    for (int d = 0; d < 64; d += 4) {
      float4 qv = *(const float4*)&qs[r][d];
      float4 ka = *(const float4*)&ks[kk0 + 0][d];
      float4 kb = *(const float4*)&ks[kk0 + 1][d];
      float4 kc = *(const float4*)&ks[kk0 + 2][d];
      float4 kd = *(const float4*)&ks[kk0 + 3][d];
      s0 += qv.x * ka.x + qv.y * ka.y + qv.z * ka.z + qv.w * ka.w;
      s1 += qv.x * kb.x + qv.y * kb.y + qv.z * kb.z + qv.w * kb.w;
      s2 += qv.x * kc.x + qv.y * kc.y + qv.z * kc.z + qv.w * kc.w;
      s3 += qv.x * kd.x + qv.y * kd.y + qv.z * kd.z + qv.w * kd.w;
    }
    const int kvalid = S - kt * 32;
    s0 = (kk0 + 0 < kvalid) ? s0 * 0.125f : -1e30f;
    s1 = (kk0 + 1 < kvalid) ? s1 * 0.125f : -1e30f;
    s2 = (kk0 + 2 < kvalid) ? s2 * 0.125f : -1e30f;
    s3 = (kk0 + 3 < kvalid) ? s3 * 0.125f : -1e30f;
    float mx = fmaxf(fmaxf(s0, s1), fmaxf(s2, s3));
    mx = fmaxf(mx, __shfl_xor(mx, 1, 64));
    mx = fmaxf(mx, __shfl_xor(mx, 2, 64));
    mx = fmaxf(mx, __shfl_xor(mx, 4, 64));
    float mnew = fmaxf(m, mx);
    float sc = __expf(m - mnew);
    float p0 = __expf(s0 - mnew), p1 = __expf(s1 - mnew);
    float p2 = __expf(s2 - mnew), p3 = __expf(s3 - mnew);
    float rs = p0 + p1 + p2 + p3;
    rs += __shfl_xor(rs, 1, 64);
    rs += __shfl_xor(rs, 2, 64);
    rs += __shfl_xor(rs, 4, 64);
    l = l * sc + rs;
    m = mnew;
    o0 *= sc; o1 *= sc; o2 *= sc; o3 *= sc; o4 *= sc; o5 *= sc; o6 *= sc; o7 *= sc;
    ps[r][kk0 + 0] = p0; ps[r][kk0 + 1] = p1; ps[r][kk0 + 2] = p2; ps[r][kk0 + 3] = p3;
    __syncthreads();
    const int c0 = j << 3;
#pragma unroll
    for (int kk = 0; kk < 32; ++kk) {
      float p = ps[r][kk];
      float4 va = *(const float4*)&vs[kk][c0];
      float4 vb = *(const float4*)&vs[kk][c0 + 4];
      o0 += p * va.x; o1 += p * va.y; o2 += p * va.z; o3 += p * va.w;
      o4 += p * vb.x; o5 += p * vb.y; o6 += p * vb.z; o7 += p * vb.w;
    }
  }
  int qrow = qt * 32 + r;
  if (qrow < S) {
    float inv = 1.0f / l;
    float4 ra, rb;
    ra.x = o0 * inv; ra.y = o1 * inv; ra.z = o2 * inv; ra.w = o3 * inv;
    rb.x = o4 * inv; rb.y = o5 * inv; rb.z = o6 * inv; rb.w = o7 * inv;
    size_t base = ((size_t)bs * S + qrow) * D + h * DHH + (j << 3);
    *(float4*)&yg[base] = ra;
    *(float4*)&yg[base + 4] = rb;
  }
}

// ---------------- foreign-key scan pieces ----------------
__global__ __launch_bounds__(256) void zero_kernel(float* __restrict__ p, int n) {
  int i = blockIdx.x * 256 + threadIdx.x;
  if (i < n) p[i] = 0.f;
}

__global__ __launch_bounds__(256) void fk_compute(
    const float* __restrict__ tc, const int* __restrict__ pnums, const int* __restrict__ fkeys,
    const float* __restrict__ W, float* __restrict__ scr, int e, int which) {
  const int tid = threadIdx.x;
  const int b = blockIdx.y;
  const int i0 = fkeys[(b * FEDGE + e) * 2 + 0];
  const int i1 = fkeys[(b * FEDGE + e) * 2 + 1];
  const int fp = pnums[b * PPAR + i0];
  const int pp = pnums[b * PPAR + i1];
  const int src = which ? fp : pp;
  const int k0 = blockIdx.z << 8;
  __shared__ float sa[3][256];
#pragma unroll
  for (int i = 0; i < 3; ++i)
    sa[i][tid] = tc[(((size_t)(b * TT + src)) * CCOL + i) * D + k0 + tid];
  __syncthreads();
  const int col = (blockIdx.x << 8) + tid;
  float a0 = 0, a1 = 0, a2 = 0;
#pragma unroll 8
  for (int kk = 0; kk < 256; ++kk) {
    float w = W[(size_t)(k0 + kk) * D + col];
    a0 += sa[0][kk] * w;
    a1 += sa[1][kk] * w;
    a2 += sa[2][kk] * w;
  }
  atomicAdd(&scr[(b * 3 + 0) * D + col], a0);
  atomicAdd(&scr[(b * 3 + 1) * D + col], a1);
  atomicAdd(&scr[(b * 3 + 2) * D + col], a2);
}

__global__ __launch_bounds__(256) void fk_add(
    float* __restrict__ tc, const int* __restrict__ pnums, const int* __restrict__ fkeys,
    const float* __restrict__ bias, const float* __restrict__ scr, int e, int which) {
  int idx = blockIdx.x * 256 + threadIdx.x;
  int col = idx & 1023;
  int bi = idx >> 10;
  int b = bi / 3, i = bi % 3;
  const int i0 = fkeys[(b * FEDGE + e) * 2 + 0];
  const int i1 = fkeys[(b * FEDGE + e) * 2 + 1];
  const int fp = pnums[b * PPAR + i0];
  const int pp = pnums[b * PPAR + i1];
  const int dst = which ? pp : fp;
  float val = tanhf(scr[idx] + bias[col]);
  tc[(((size_t)(b * TT + dst)) * CCOL + i) * D + col] += val;
}

// ---------------- host-side orchestration ----------------
static void cvt_split(const float* x, unsigned short* hi, unsigned short* lo, int n, hipStream_t st) {
  int n4 = n >> 2;
  int g = (n4 + 255) / 256;
  if (g > 2048) g = 2048;
  split_kernel<<<g, 256, 0, st>>>(x, hi, lo, n4);
}

static void cvt_splitT(const float* W, unsigned short* hi, unsigned short* lo, int K, int N, hipStream_t st) {
  splitT_kernel<<<dim3(N >> 5, K >> 5), 256, 0, st>>>(W, hi, lo, K, N);
}

static void mgemm(int mode, const unsigned short* Ah, const unsigned short* Al,
                  const unsigned short* Bh, const unsigned short* Bl,
                  const float* bias, const float* Rs, float* Co,
                  unsigned short* Ch, unsigned short* Cl,
                  int M, int N, int K, hipStream_t st) {
  dim3 g(N >> 7, M >> 7);
  if (mode == 0)
    mfma_gemm<0><<<g, 256, 0, st>>>(Ah, Al, Bh, Bl, bias, Rs, Co, Ch, Cl, M, N, K);
  else if (mode == 1)
    mfma_gemm<1><<<g, 256, 0, st>>>(Ah, Al, Bh, Bl, bias, Rs, Co, Ch, Cl, M, N, K);
  else
    mfma_gemm<2><<<g, 256, 0, st>>>(Ah, Al, Bh, Bl, bias, Rs, Co, Ch, Cl, M, N, K);
}

static void run_layer(float* xp, int l, int M, int Bseq, int S,
                      const float* qkvw, const float* qkvb, const float* ow, const float* ob,
                      const float* ln1, const float* w1, const float* b1,
                      const float* w2, const float* b2, const float* ln2,
                      float* q, float* k, float* v, float* y,
                      unsigned short* Ah, unsigned short* Al,
                      unsigned short* Wth, unsigned short* Wtl,
                      unsigned short* Hh, unsigned short* Hl, hipStream_t st) {
  const size_t dd = (size_t)D * D;
  cvt_split(xp, Ah, Al, M * D, st);
  for (int j = 0; j < 3; ++j) {
    cvt_splitT(qkvw + (size_t)(l * 3 + j) * dd, Wth, Wtl, D, D, st);
    float* out = (j == 0) ? q : (j == 1) ? k : v;
    mgemm(0, Ah, Al, Wth, Wtl, qkvb + (size_t)(l * 3 + j) * D, nullptr, out, nullptr, nullptr, M, D, D, st);
  }
  attn_kernel<<<dim3((S + 31) / 32, NH, Bseq), 256, 0, st>>>(q, k, v, y, S);
  cvt_split(y, Ah, Al, M * D, st);
  cvt_splitT(ow + (size_t)l * dd, Wth, Wtl, D, D, st);
  mgemm(1, Ah, Al, Wth, Wtl, ob + (size_t)l * D, xp, xp, nullptr, nullptr, M, D, D, st);
  ln_kernel<<<M, 256, 0, st>>>(xp, ln1 + (size_t)l * 2 * D);
  cvt_split(xp, Ah, Al, M * D, st);
  cvt_splitT(w1 + (size_t)l * D * DFF, Wth, Wtl, D, DFF, st);
  mgemm(2, Ah, Al, Wth, Wtl, b1 + (size_t)l * DFF, nullptr, nullptr, Hh, Hl, M, DFF, D, st);
  cvt_splitT(w2 + (size_t)l * DFF * D, Wth, Wtl, DFF, D, st);
  mgemm(1, Hh, Hl, Wth, Wtl, b2 + (size_t)l * D, xp, xp, nullptr, nullptr, M, D, DFF, st);
  ln_kernel<<<M, 256, 0, st>>>(xp, ln2 + (size_t)l * 2 * D);
}

extern "C" void kernel_launch(void* const* d_in, const int* in_sizes, int n_in,
                              void* d_out, int out_size, void* d_ws, size_t ws_size,
                              hipStream_t stream) {
  (void)in_sizes; (void)n_in; (void)out_size; (void)ws_size;
  const int* input_ids = (const int*)d_in[0];
  const int* table_cols = (const int*)d_in[1];
  const int* tc_types = (const int*)d_in[2];
  const int* pnums = (const int*)d_in[3];
  const int* fkeys = (const int*)d_in[4];
  const float* wemb = (const float*)d_in[9];
  const float* pemb = (const float*)d_in[10];
  const float* temb = (const float*)d_in[11];
  const float* embln = (const float*)d_in[12];
  const float* qkvw = (const float*)d_in[13];
  const float* qkvb = (const float*)d_in[14];
  const float* ow = (const float*)d_in[15];
  const float* ob = (const float*)d_in[16];
  const float* ln1 = (const float*)d_in[17];
  const float* w1 = (const float*)d_in[18];
  const float* b1 = (const float*)d_in[19];
  const float* w2 = (const float*)d_in[20];
  const float* b2 = (const float*)d_in[21];
  const float* ln2 = (const float*)d_in[22];
  const float* primw = (const float*)d_in[23];
  const float* primb = (const float*)d_in[24];
  const float* forw = (const float*)d_in[25];
  const float* forb = (const float*)d_in[26];

  float* x = (float*)d_out;                 // [32, 376, 1024]
  const size_t SZ = (size_t)M_TC * D;       // 15.7M elements
  float* q = (float*)d_ws;                  // 4 x SZ fp32
  float* kb = q + SZ;
  float* vb = kb + SZ;
  float* yb = vb + SZ;
  float* tc = yb + SZ;                      // SZ fp32
  unsigned short* Hh = (unsigned short*)q;  // FFN hidden hi: M_TC*DFF bf16 = 2*SZ fp32 (overlays q,kb)
  unsigned short* Hl = (unsigned short*)vb; // overlays vb,yb
  unsigned short* Ah = (unsigned short*)(tc + SZ);  // SZ bf16
  unsigned short* Al = Ah + SZ;                     // SZ bf16
  unsigned short* Wth = Al + SZ;                    // D*DFF bf16
  unsigned short* Wtl = Wth + (size_t)D * DFF;      // D*DFF bf16
  float* fks = (float*)(Wtl + (size_t)D * DFF);     // 32*3*1024 fp32

  embed_q_kernel<<<BB * LQS, 256, 0, stream>>>(input_ids, wemb, pemb, temb, embln, x);
  embed_tc_kernel<<<M_TC, 256, 0, stream>>>(table_cols, tc_types, wemb, pemb, temb, embln, tc);

  run_layer(tc, 0, M_TC, BB * TT, CCOL, qkvw, qkvb, ow, ob, ln1, w1, b1, w2, b2, ln2,
            q, kb, vb, yb, Ah, Al, Wth, Wtl, Hh, Hl, stream);

  for (int e = 0; e < FEDGE; ++e) {
    for (int which = 0; which < 2; ++which) {
      zero_kernel<<<384, 256, 0, stream>>>(fks, BB * 3 * D);
      fk_compute<<<dim3(4, BB, 4), 256, 0, stream>>>(tc, pnums, fkeys,
                                                     which ? forw : primw, fks, e, which);
      fk_add<<<384, 256, 0, stream>>>(tc, pnums, fkeys, which ? forb : primb, fks, e, which);
    }
  }

  assemble_kernel<<<BB * 120, 256, 0, stream>>>(tc, pemb, temb, embln, x);

  for (int l = 1; l < 5; ++l)
    run_layer(x, l, M_MAIN, BB, S_MAIN, qkvw, qkvb, ow, ob, ln1, w1, b1, w2, b2, ln2,
              q, kb, vb, yb, Ah, Al, Wth, Wtl, Hh, Hl, stream);
}